// Round 3
// baseline (434.517 us; speedup 1.0000x reference)
//
#include <hip/hip_runtime.h>

// ---------------------------------------------------------------------------
// Multihead self-attention with RoPE, MI355X (gfx950).  Round 3.
// B=2, S=2048, H=16, DH=64, DM=1024.
// R3: flash computes S^T (operand-swapped MFMA) -> scalar l per lane, packed
// P (v_perm) with 4x ds_write_b64/ktile, exp2f softmax, peeled diagonal tile,
// balanced qt->CU map. RoPE fused into qkv epilogue (f32), casts merged.
// 4 launches total.
// ---------------------------------------------------------------------------

typedef __attribute__((ext_vector_type(8))) short bf16x8;
typedef __attribute__((ext_vector_type(4))) float f32x4;

__device__ __forceinline__ short f2bf(float f) {
  unsigned u = __float_as_uint(f);
  unsigned r = (u + 0x7fffu + ((u >> 16) & 1u)) >> 16;   // RNE
  return (short)(r & 0xFFFFu);
}

// pack two f32 -> adjacent bf16 (round-half-up via +0x8000), one v_perm_b32
__device__ __forceinline__ unsigned pk2(float a, float b) {
  return __builtin_amdgcn_perm(__float_as_uint(b) + 0x8000u,
                               __float_as_uint(a) + 0x8000u, 0x07060302u);
}

// async global->LDS, 16B per lane. LDS dest must be wave-uniform base + lane*16.
__device__ __forceinline__ void async16(const void* g, void* l) {
  __builtin_amdgcn_global_load_lds(
      (const __attribute__((address_space(1))) void*)g,
      (__attribute__((address_space(3))) void*)l, 16, 0, 0);
}

__device__ __forceinline__ void cstore(short* C, size_t i, float v) { C[i] = f2bf(v); }
__device__ __forceinline__ void cstore(float* C, size_t i, float v) { C[i] = v; }

// ---------------------------------------------------------------------------
// merged f32 -> bf16 cast: X (1M float4) then Wq|Wk|Wv|Wo (1M float4, dsts
// contiguous in ws).  8192 blocks x 256.
// ---------------------------------------------------------------------------
__global__ void cast_all(const float4* __restrict__ X,
                         const float4* __restrict__ w0, const float4* __restrict__ w1,
                         const float4* __restrict__ w2, const float4* __restrict__ w3,
                         short* __restrict__ Xb, short* __restrict__ Wb) {
  int t = blockIdx.x * 256 + threadIdx.x;
  const float4* s;
  short4* d;
  if (t < (1 << 20)) {
    s = X + t; d = (short4*)Xb + t;
  } else {
    int u = t - (1 << 20);
    int which = u >> 18;
    s = ((which == 0) ? w0 : (which == 1) ? w1 : (which == 2) ? w2 : w3) + (u & 0x3FFFF);
    d = (short4*)Wb + u;
  }
  float4 v = *s;
  *d = make_short4(f2bf(v.x), f2bf(v.y), f2bf(v.z), f2bf(v.w));
}

// ---------------------------------------------------------------------------
// bf16 GEMM core: C[M,N] = A[M,K] * B[N,K]^T, K=1024, lda=ldb=1024.
// BM=128, BN=32*NF. 256 threads = 4 waves (2x2). Double-buffered LDS.
// ROPE: apply rotary embedding to the f32 acc in the epilogue (rows = tokens,
// cols = embed dim; interleaved pairs exchanged via shfl_xor(1)).
// ---------------------------------------------------------------------------
template <typename OUT, int NF, bool ROPE>
__device__ __forceinline__ void gemm_core(const short* __restrict__ A, const short* __restrict__ B,
                                          OUT* __restrict__ C, int bm, int bn, int ldc,
                                          const int* __restrict__ pos) {
  constexpr int BN = 32 * NF;
  __shared__ __align__(16) short As[2][128 * 32];
  __shared__ __align__(16) short Bs[2][BN * 32];
  const int tid  = threadIdx.x;
  const int lane = tid & 63, wave = tid >> 6;
  const int col  = lane & 15, quad = lane >> 4;
  const int wm = (wave & 1) * 64, wn = (wave >> 1) * (16 * NF);

  f32x4 acc[4][NF];
#pragma unroll
  for (int i = 0; i < 4; i++)
#pragma unroll
    for (int j = 0; j < NF; j++) acc[i][j] = (f32x4){0.f, 0.f, 0.f, 0.f};

  auto stage = [&](int k0, int bu) {
#pragma unroll
    for (int c = tid; c < 512; c += 256) {
      int r = c >> 2, cc = (c & 3) << 3;
      async16(A + (size_t)(bm + r) * 1024 + k0 + cc, As[bu] + c * 8);
    }
#pragma unroll
    for (int c = tid; c < BN * 4; c += 256) {
      int r = c >> 2, cc = (c & 3) << 3;
      async16(B + (size_t)(bn + r) * 1024 + k0 + cc, Bs[bu] + c * 8);
    }
  };

  stage(0, 0);
  for (int it = 0; it < 32; ++it) {
    __syncthreads();
    if (it < 31) stage((it + 1) * 32, (it + 1) & 1);
    const short* as = As[it & 1];
    const short* bs = Bs[it & 1];

    bf16x8 af[4], bfr[NF];
#pragma unroll
    for (int i = 0; i < 4; i++)
      af[i] = *(const bf16x8*)(as + (wm + i * 16 + col) * 32 + quad * 8);
#pragma unroll
    for (int i = 0; i < NF; i++)
      bfr[i] = *(const bf16x8*)(bs + (wn + i * 16 + col) * 32 + quad * 8);
#pragma unroll
    for (int mi = 0; mi < 4; mi++)
#pragma unroll
      for (int ni = 0; ni < NF; ni++)
        acc[mi][ni] = __builtin_amdgcn_mfma_f32_16x16x32_bf16(af[mi], bfr[ni], acc[mi][ni], 0, 0, 0);
  }

  if (ROPE) {
    float invf[NF];
#pragma unroll
    for (int ni = 0; ni < NF; ni++) {
      int pr = ((bn + wn + ni * 16 + col) & 63) >> 1;
      invf[ni] = exp2f(-0.4152410118609203f * (float)pr);   // 10000^(-pr/32)
    }
    const float sgn = (col & 1) ? 1.f : -1.f;
#pragma unroll
    for (int mi = 0; mi < 4; mi++) {
#pragma unroll
      for (int r = 0; r < 4; r++) {
        int row = bm + wm + mi * 16 + quad * 4 + r;
        float fp = (float)pos[row & 2047];
#pragma unroll
        for (int ni = 0; ni < NF; ni++) {
          float ang = fp * invf[ni];
          float sn, cs;
          sincosf(ang, &sn, &cs);
          float x  = acc[mi][ni][r];
          float px = __shfl_xor(x, 1);               // pair partner (col^1)
          acc[mi][ni][r] = fmaf(x, cs, sgn * px * sn);
        }
      }
    }
  }

#pragma unroll
  for (int mi = 0; mi < 4; mi++) {
#pragma unroll
    for (int r = 0; r < 4; r++) {
      size_t row = (size_t)(bm + wm + mi * 16 + quad * 4 + r);
#pragma unroll
      for (int ni = 0; ni < NF; ni++) {
        int cg = bn + wn + ni * 16 + col;
        cstore(C, row * ldc + cg, acc[mi][ni][r]);
      }
    }
  }
}

// z=0: Q = rope(X Wq^T); z=1: K = rope(X Wk^T); z=2: Vt = Wv X^T.
__global__ __launch_bounds__(256) void qkv_gemm(const short* __restrict__ Xb,
                                                const short* __restrict__ Wq,
                                                const short* __restrict__ Wk,
                                                const short* __restrict__ Wv,
                                                short* __restrict__ Qo,
                                                short* __restrict__ Ko,
                                                short* __restrict__ Vto,
                                                const int* __restrict__ pos) {
  const int z = blockIdx.z;
  if (z == 0)      gemm_core<short, 4, true >(Xb, Wq, Qo, blockIdx.x * 128, blockIdx.y * 128, 1024, pos);
  else if (z == 1) gemm_core<short, 4, true >(Xb, Wk, Ko, blockIdx.x * 128, blockIdx.y * 128, 1024, pos);
  else             gemm_core<short, 4, false>(Wv, Xb, Vto, blockIdx.y * 128, blockIdx.x * 128, 4096, pos);
}

__global__ __launch_bounds__(256) void out_gemm(const short* __restrict__ Ctx,
                                                const short* __restrict__ Wo,
                                                float* __restrict__ C) {
  gemm_core<float, 2, false>(Ctx, Wo, C, blockIdx.x * 128, blockIdx.y * 64, 1024, nullptr);
}

// ---------------------------------------------------------------------------
// Flash attention, causal. grid (bh=32, y=32->qt balanced), 4 waves,
// wave owns 16 q-rows. S^T MFMA (A=K, B=Q): lane holds one q (=col) and 16
// keys -> scalar l, packed-P b64 writes, exp2f softmax, diagonal tile peeled.
// LDS = 16K Ks + 16K Vs + 8K Ps = 40960 B -> 4 blocks/CU.
// ---------------------------------------------------------------------------
__global__ __launch_bounds__(256) void flash_attn(const short* __restrict__ Q,
                                                  const short* __restrict__ K,
                                                  const short* __restrict__ Vt,
                                                  short* __restrict__ ctx) {
  // balanced qt map: each CU's 4 resident blocks (y = a+8k) sum to 68 ktiles
  const int y = blockIdx.y, a = y & 7, kk = y >> 3;
  const int qt = (kk == 0) ? 2 * a : (kk == 1) ? 31 - 2 * a : (kk == 2) ? 2 * a + 1 : 30 - 2 * a;
  const int bh = blockIdx.x;
  const int b = bh >> 4, h = bh & 15;
  __shared__ __align__(16) short Ks[2][64 * 64];   // [key][d], chunk-swizzled
  __shared__ __align__(16) short Vs[2][64 * 64];   // [d][key], chunk-swizzled
  __shared__ __align__(16) short Ps[4][16 * 64];   // per-wave P [q][key], chunk-swizzled
  const int tid = threadIdx.x, lane = tid & 63, wave = tid >> 6;
  const int col = lane & 15, quad = lane >> 4;

  // Q fragments (B-operand: [n=lane&15][k=quad*8+j]) in registers
  const size_t qrow = (size_t)(b * 2048 + qt * 64 + wave * 16 + col);
  bf16x8 qf0 = *(const bf16x8*)(Q + qrow * 1024 + h * 64 + quad * 8);
  bf16x8 qf1 = *(const bf16x8*)(Q + qrow * 1024 + h * 64 + 32 + quad * 8);

  float l_i = 0.f;                                  // one q per lane (q = col)
  f32x4 o_acc[4];
#pragma unroll
  for (int i = 0; i < 4; i++) o_acc[i] = (f32x4){0.f, 0.f, 0.f, 0.f};

  auto stage = [&](int kt, int bu) {
#pragma unroll
    for (int i = 0; i < 2; i++) {
      int c = i * 256 + tid;
      int r = c >> 3;
      int g = ((c & 7) ^ (r & 7)) << 3;
      async16(K  + (size_t)(b * 2048 + kt * 64 + r) * 1024 + h * 64 + g, Ks[bu] + c * 8);
      async16(Vt + (size_t)(h * 64 + r) * 4096 + b * 2048 + kt * 64 + g, Vs[bu] + c * 8);
    }
  };

  // precomputed LDS offsets (shorts)
  int pswr[4], psrd0, psrd1;
#pragma unroll
  for (int nb = 0; nb < 4; nb++) {
    int c8 = nb * 2 + (quad >> 1);
    pswr[nb] = col * 64 + ((c8 ^ (col & 7)) << 3) + (quad & 1) * 4;
  }
  psrd0 = col * 64 + ((quad ^ (col & 7)) << 3);
  psrd1 = col * 64 + (((quad + 4) ^ (col & 7)) << 3);

  const float C1 = 0.18033688011112042f;   // 0.125 * log2(e)
  const float C2 = 17.31234049066756f;     // 12 * log2(e)

  auto tile = [&](int kt, bool diag) {
    const short* ks = Ks[kt & 1];
    const short* vs = Vs[kt & 1];
    // S^T = K Q^T : rows = keys, cols = q
    f32x4 s_acc[4];
#pragma unroll
    for (int nb = 0; nb < 4; nb++) {
      int row = nb * 16 + col;
      bf16x8 k0 = *(const bf16x8*)(ks + (row * 8 + (quad ^ (row & 7))) * 8);
      bf16x8 k1 = *(const bf16x8*)(ks + (row * 8 + ((quad + 4) ^ (row & 7))) * 8);
      f32x4 z = (f32x4){0.f, 0.f, 0.f, 0.f};
      z = __builtin_amdgcn_mfma_f32_16x16x32_bf16(k0, qf0, z, 0, 0, 0);
      z = __builtin_amdgcn_mfma_f32_16x16x32_bf16(k1, qf1, z, 0, 0, 0);
      s_acc[nb] = z;
    }
    // softmax (fixed max shift 12) + pack + b64 write
#pragma unroll
    for (int nb = 0; nb < 4; nb++) {
      float p[4];
#pragma unroll
      for (int r = 0; r < 4; r++) {
        p[r] = exp2f(s_acc[nb][r] * C1 - C2);
        if (diag && (nb * 16 + quad * 4 + r) > (wave * 16 + col)) p[r] = 0.f;
        l_i += p[r];
      }
      *(uint2*)(&Ps[wave][pswr[nb]]) = make_uint2(pk2(p[0], p[1]), pk2(p[2], p[3]));
    }
    bf16x8 af0 = *(const bf16x8*)(&Ps[wave][psrd0]);
    bf16x8 af1 = *(const bf16x8*)(&Ps[wave][psrd1]);
#pragma unroll
    for (int nb = 0; nb < 4; nb++) {
      int row = nb * 16 + col;
      bf16x8 v0 = *(const bf16x8*)(vs + (row * 8 + (quad ^ (row & 7))) * 8);
      bf16x8 v1 = *(const bf16x8*)(vs + (row * 8 + ((quad + 4) ^ (row & 7))) * 8);
      o_acc[nb] = __builtin_amdgcn_mfma_f32_16x16x32_bf16(af0, v0, o_acc[nb], 0, 0, 0);
      o_acc[nb] = __builtin_amdgcn_mfma_f32_16x16x32_bf16(af1, v1, o_acc[nb], 0, 0, 0);
    }
  };

  stage(0, 0);
  for (int kt = 0; kt < qt; ++kt) {                 // mask-free main loop
    __syncthreads();
    stage(kt + 1, (kt + 1) & 1);
    tile(kt, false);
  }
  __syncthreads();
  tile(qt, true);                                   // peeled diagonal tile

  // l reduction over the 4 quads sharing this col, then per-row broadcast
  l_i += __shfl_xor(l_i, 16);
  l_i += __shfl_xor(l_i, 32);
  float invl = 1.0f / l_i;

#pragma unroll
  for (int r = 0; r < 4; r++) {
    float inv = __shfl(invl, quad * 4 + r);         // lane holding q-row quad*4+r
    size_t row = (size_t)(b * 2048 + qt * 64 + wave * 16 + quad * 4 + r);
#pragma unroll
    for (int nb = 0; nb < 4; nb++)
      ctx[row * 1024 + h * 64 + nb * 16 + col] = f2bf(o_acc[nb][r] * inv);
  }
}

// ---------------------------------------------------------------------------
extern "C" void kernel_launch(void* const* d_in, const int* in_sizes, int n_in,
                              void* d_out, int out_size, void* d_ws, size_t ws_size,
                              hipStream_t stream) {
  const float* X  = (const float*)d_in[0];
  const int* pos  = (const int*)d_in[1];
  const float* wq = (const float*)d_in[2];
  const float* wk = (const float*)d_in[3];
  const float* wv = (const float*)d_in[4];
  const float* wo = (const float*)d_in[5];
  float* out = (float*)d_out;

  short* Xb  = (short*)d_ws;
  short* Wqb = Xb + (1 << 22);
  short* Wkb = Wqb + (1 << 20);
  short* Wvb = Wkb + (1 << 20);
  short* Wob = Wvb + (1 << 20);
  short* Qb  = Wob + (1 << 20);
  short* Kb  = Qb + (1 << 22);
  short* Vtb = Kb + (1 << 22);
  short* Ctx = Vtb + (1 << 22);

  cast_all<<<8192, 256, 0, stream>>>((const float4*)X, (const float4*)wq, (const float4*)wk,
                                     (const float4*)wv, (const float4*)wo, Xb, Wqb);
  qkv_gemm<<<dim3(32, 8, 3), 256, 0, stream>>>(Xb, Wqb, Wkb, Wvb, Qb, Kb, Vtb, pos);
  flash_attn<<<dim3(32, 32), 256, 0, stream>>>(Qb, Kb, Vtb, Ctx);
  out_gemm<<<dim3(32, 16), 256, 0, stream>>>(Ctx, Wob, out);
}

// Round 4
// 193.904 us; speedup vs baseline: 2.2409x; 2.2409x over previous
//
#include <hip/hip_runtime.h>

// ---------------------------------------------------------------------------
// Multihead self-attention with RoPE, MI355X (gfx950).  Round 4.
// B=2, S=2048, H=16, DH=64, DM=1024.
// R4: R3's libm sincosf in the qkv epilogue hit the Payne-Hanek slow path
// (scratch arrays -> 1 GB spill writes, 226 MB I$/scratch fetch, 300 us).
// Replaced with hardware v_sin/v_cos in REVOLUTIONS + explicit fract
// reduction (angle err ~1e-4 rad << bf16 noise). Everything else unchanged.
// ---------------------------------------------------------------------------

typedef __attribute__((ext_vector_type(8))) short bf16x8;
typedef __attribute__((ext_vector_type(4))) float f32x4;

__device__ __forceinline__ short f2bf(float f) {
  unsigned u = __float_as_uint(f);
  unsigned r = (u + 0x7fffu + ((u >> 16) & 1u)) >> 16;   // RNE
  return (short)(r & 0xFFFFu);
}

// pack two f32 -> adjacent bf16 (round-half-up via +0x8000), one v_perm_b32
__device__ __forceinline__ unsigned pk2(float a, float b) {
  return __builtin_amdgcn_perm(__float_as_uint(b) + 0x8000u,
                               __float_as_uint(a) + 0x8000u, 0x07060302u);
}

// async global->LDS, 16B per lane. LDS dest must be wave-uniform base + lane*16.
__device__ __forceinline__ void async16(const void* g, void* l) {
  __builtin_amdgcn_global_load_lds(
      (const __attribute__((address_space(1))) void*)g,
      (__attribute__((address_space(3))) void*)l, 16, 0, 0);
}

__device__ __forceinline__ void cstore(short* C, size_t i, float v) { C[i] = f2bf(v); }
__device__ __forceinline__ void cstore(float* C, size_t i, float v) { C[i] = v; }

// ---------------------------------------------------------------------------
// merged f32 -> bf16 cast: X (1M float4) then Wq|Wk|Wv|Wo (dsts contiguous).
// ---------------------------------------------------------------------------
__global__ void cast_all(const float4* __restrict__ X,
                         const float4* __restrict__ w0, const float4* __restrict__ w1,
                         const float4* __restrict__ w2, const float4* __restrict__ w3,
                         short* __restrict__ Xb, short* __restrict__ Wb) {
  int t = blockIdx.x * 256 + threadIdx.x;
  const float4* s;
  short4* d;
  if (t < (1 << 20)) {
    s = X + t; d = (short4*)Xb + t;
  } else {
    int u = t - (1 << 20);
    int which = u >> 18;
    s = ((which == 0) ? w0 : (which == 1) ? w1 : (which == 2) ? w2 : w3) + (u & 0x3FFFF);
    d = (short4*)Wb + u;
  }
  float4 v = *s;
  *d = make_short4(f2bf(v.x), f2bf(v.y), f2bf(v.z), f2bf(v.w));
}

// ---------------------------------------------------------------------------
// bf16 GEMM core: C[M,N] = A[M,K] * B[N,K]^T, K=1024, lda=ldb=1024.
// BM=128, BN=32*NF. 256 threads = 4 waves (2x2). Double-buffered LDS.
// ROPE: rotary on the f32 acc in the epilogue; sin/cos via HW v_sin/v_cos in
// revolutions with explicit fract reduction (no libm slow path!).
// ---------------------------------------------------------------------------
template <typename OUT, int NF, bool ROPE>
__device__ __forceinline__ void gemm_core(const short* __restrict__ A, const short* __restrict__ B,
                                          OUT* __restrict__ C, int bm, int bn, int ldc,
                                          const int* __restrict__ pos) {
  constexpr int BN = 32 * NF;
  __shared__ __align__(16) short As[2][128 * 32];
  __shared__ __align__(16) short Bs[2][BN * 32];
  const int tid  = threadIdx.x;
  const int lane = tid & 63, wave = tid >> 6;
  const int col  = lane & 15, quad = lane >> 4;
  const int wm = (wave & 1) * 64, wn = (wave >> 1) * (16 * NF);

  f32x4 acc[4][NF];
#pragma unroll
  for (int i = 0; i < 4; i++)
#pragma unroll
    for (int j = 0; j < NF; j++) acc[i][j] = (f32x4){0.f, 0.f, 0.f, 0.f};

  auto stage = [&](int k0, int bu) {
#pragma unroll
    for (int c = tid; c < 512; c += 256) {
      int r = c >> 2, cc = (c & 3) << 3;
      async16(A + (size_t)(bm + r) * 1024 + k0 + cc, As[bu] + c * 8);
    }
#pragma unroll
    for (int c = tid; c < BN * 4; c += 256) {
      int r = c >> 2, cc = (c & 3) << 3;
      async16(B + (size_t)(bn + r) * 1024 + k0 + cc, Bs[bu] + c * 8);
    }
  };

  stage(0, 0);
  for (int it = 0; it < 32; ++it) {
    __syncthreads();
    if (it < 31) stage((it + 1) * 32, (it + 1) & 1);
    const short* as = As[it & 1];
    const short* bs = Bs[it & 1];

    bf16x8 af[4], bfr[NF];
#pragma unroll
    for (int i = 0; i < 4; i++)
      af[i] = *(const bf16x8*)(as + (wm + i * 16 + col) * 32 + quad * 8);
#pragma unroll
    for (int i = 0; i < NF; i++)
      bfr[i] = *(const bf16x8*)(bs + (wn + i * 16 + col) * 32 + quad * 8);
#pragma unroll
    for (int mi = 0; mi < 4; mi++)
#pragma unroll
      for (int ni = 0; ni < NF; ni++)
        acc[mi][ni] = __builtin_amdgcn_mfma_f32_16x16x32_bf16(af[mi], bfr[ni], acc[mi][ni], 0, 0, 0);
  }

  if (ROPE) {
    // invf_rev = 10000^(-pr/32) / (2*pi)  -> angle in revolutions
    float invf_rev[NF];
#pragma unroll
    for (int ni = 0; ni < NF; ni++) {
      int pr = ((bn + wn + ni * 16 + col) & 63) >> 1;
      invf_rev[ni] = exp2f(-0.4152410118609203f * (float)pr) * 0.15915494309189535f;
    }
    const float sgn = (col & 1) ? 1.f : -1.f;
#pragma unroll
    for (int mi = 0; mi < 4; mi++) {
#pragma unroll
      for (int r = 0; r < 4; r++) {
        int row = bm + wm + mi * 16 + quad * 4 + r;
        float fp = (float)pos[row & 2047];
#pragma unroll
        for (int ni = 0; ni < NF; ni++) {
          float rev = fp * invf_rev[ni];
          rev -= floorf(rev);                         // v_fract reduction
          float sn = __builtin_amdgcn_sinf(rev);      // sin(2*pi*rev)
          float cs = __builtin_amdgcn_cosf(rev);
          float x  = acc[mi][ni][r];
          float px = __shfl_xor(x, 1);                // pair partner (col^1)
          acc[mi][ni][r] = fmaf(x, cs, sgn * px * sn);
        }
      }
    }
  }

#pragma unroll
  for (int mi = 0; mi < 4; mi++) {
#pragma unroll
    for (int r = 0; r < 4; r++) {
      size_t row = (size_t)(bm + wm + mi * 16 + quad * 4 + r);
#pragma unroll
      for (int ni = 0; ni < NF; ni++) {
        int cg = bn + wn + ni * 16 + col;
        cstore(C, row * ldc + cg, acc[mi][ni][r]);
      }
    }
  }
}

// z=0: Q = rope(X Wq^T); z=1: K = rope(X Wk^T); z=2: Vt = Wv X^T.
__global__ __launch_bounds__(256) void qkv_gemm(const short* __restrict__ Xb,
                                                const short* __restrict__ Wq,
                                                const short* __restrict__ Wk,
                                                const short* __restrict__ Wv,
                                                short* __restrict__ Qo,
                                                short* __restrict__ Ko,
                                                short* __restrict__ Vto,
                                                const int* __restrict__ pos) {
  const int z = blockIdx.z;
  if (z == 0)      gemm_core<short, 4, true >(Xb, Wq, Qo, blockIdx.x * 128, blockIdx.y * 128, 1024, pos);
  else if (z == 1) gemm_core<short, 4, true >(Xb, Wk, Ko, blockIdx.x * 128, blockIdx.y * 128, 1024, pos);
  else             gemm_core<short, 4, false>(Wv, Xb, Vto, blockIdx.y * 128, blockIdx.x * 128, 4096, pos);
}

__global__ __launch_bounds__(256) void out_gemm(const short* __restrict__ Ctx,
                                                const short* __restrict__ Wo,
                                                float* __restrict__ C) {
  gemm_core<float, 2, false>(Ctx, Wo, C, blockIdx.x * 128, blockIdx.y * 64, 1024, nullptr);
}

// ---------------------------------------------------------------------------
// Flash attention, causal. grid (bh=32, y=32->qt balanced), 4 waves,
// wave owns 16 q-rows. S^T MFMA (A=K, B=Q): lane holds one q (=col) and 16
// keys -> scalar l, packed-P b64 writes, exp2f softmax, diagonal tile peeled.
// LDS = 16K Ks + 16K Vs + 8K Ps = 40960 B -> 4 blocks/CU.
// ---------------------------------------------------------------------------
__global__ __launch_bounds__(256) void flash_attn(const short* __restrict__ Q,
                                                  const short* __restrict__ K,
                                                  const short* __restrict__ Vt,
                                                  short* __restrict__ ctx) {
  const int y = blockIdx.y, a = y & 7, kk = y >> 3;
  const int qt = (kk == 0) ? 2 * a : (kk == 1) ? 31 - 2 * a : (kk == 2) ? 2 * a + 1 : 30 - 2 * a;
  const int bh = blockIdx.x;
  const int b = bh >> 4, h = bh & 15;
  __shared__ __align__(16) short Ks[2][64 * 64];   // [key][d], chunk-swizzled
  __shared__ __align__(16) short Vs[2][64 * 64];   // [d][key], chunk-swizzled
  __shared__ __align__(16) short Ps[4][16 * 64];   // per-wave P [q][key], chunk-swizzled
  const int tid = threadIdx.x, lane = tid & 63, wave = tid >> 6;
  const int col = lane & 15, quad = lane >> 4;

  const size_t qrow = (size_t)(b * 2048 + qt * 64 + wave * 16 + col);
  bf16x8 qf0 = *(const bf16x8*)(Q + qrow * 1024 + h * 64 + quad * 8);
  bf16x8 qf1 = *(const bf16x8*)(Q + qrow * 1024 + h * 64 + 32 + quad * 8);

  float l_i = 0.f;                                  // one q per lane (q = col)
  f32x4 o_acc[4];
#pragma unroll
  for (int i = 0; i < 4; i++) o_acc[i] = (f32x4){0.f, 0.f, 0.f, 0.f};

  auto stage = [&](int kt, int bu) {
#pragma unroll
    for (int i = 0; i < 2; i++) {
      int c = i * 256 + tid;
      int r = c >> 3;
      int g = ((c & 7) ^ (r & 7)) << 3;
      async16(K  + (size_t)(b * 2048 + kt * 64 + r) * 1024 + h * 64 + g, Ks[bu] + c * 8);
      async16(Vt + (size_t)(h * 64 + r) * 4096 + b * 2048 + kt * 64 + g, Vs[bu] + c * 8);
    }
  };

  int pswr[4], psrd0, psrd1;
#pragma unroll
  for (int nb = 0; nb < 4; nb++) {
    int c8 = nb * 2 + (quad >> 1);
    pswr[nb] = col * 64 + ((c8 ^ (col & 7)) << 3) + (quad & 1) * 4;
  }
  psrd0 = col * 64 + ((quad ^ (col & 7)) << 3);
  psrd1 = col * 64 + (((quad + 4) ^ (col & 7)) << 3);

  const float C1 = 0.18033688011112042f;   // 0.125 * log2(e)
  const float C2 = 17.31234049066756f;     // 12 * log2(e)

  auto tile = [&](int kt, bool diag) {
    const short* ks = Ks[kt & 1];
    const short* vs = Vs[kt & 1];
    f32x4 s_acc[4];
#pragma unroll
    for (int nb = 0; nb < 4; nb++) {
      int row = nb * 16 + col;
      bf16x8 k0 = *(const bf16x8*)(ks + (row * 8 + (quad ^ (row & 7))) * 8);
      bf16x8 k1 = *(const bf16x8*)(ks + (row * 8 + ((quad + 4) ^ (row & 7))) * 8);
      f32x4 z = (f32x4){0.f, 0.f, 0.f, 0.f};
      z = __builtin_amdgcn_mfma_f32_16x16x32_bf16(k0, qf0, z, 0, 0, 0);
      z = __builtin_amdgcn_mfma_f32_16x16x32_bf16(k1, qf1, z, 0, 0, 0);
      s_acc[nb] = z;
    }
#pragma unroll
    for (int nb = 0; nb < 4; nb++) {
      float p[4];
#pragma unroll
      for (int r = 0; r < 4; r++) {
        p[r] = exp2f(s_acc[nb][r] * C1 - C2);
        if (diag && (nb * 16 + quad * 4 + r) > (wave * 16 + col)) p[r] = 0.f;
        l_i += p[r];
      }
      *(uint2*)(&Ps[wave][pswr[nb]]) = make_uint2(pk2(p[0], p[1]), pk2(p[2], p[3]));
    }
    bf16x8 af0 = *(const bf16x8*)(&Ps[wave][psrd0]);
    bf16x8 af1 = *(const bf16x8*)(&Ps[wave][psrd1]);
#pragma unroll
    for (int nb = 0; nb < 4; nb++) {
      int row = nb * 16 + col;
      bf16x8 v0 = *(const bf16x8*)(vs + (row * 8 + (quad ^ (row & 7))) * 8);
      bf16x8 v1 = *(const bf16x8*)(vs + (row * 8 + ((quad + 4) ^ (row & 7))) * 8);
      o_acc[nb] = __builtin_amdgcn_mfma_f32_16x16x32_bf16(af0, v0, o_acc[nb], 0, 0, 0);
      o_acc[nb] = __builtin_amdgcn_mfma_f32_16x16x32_bf16(af1, v1, o_acc[nb], 0, 0, 0);
    }
  };

  stage(0, 0);
  for (int kt = 0; kt < qt; ++kt) {
    __syncthreads();
    stage(kt + 1, (kt + 1) & 1);
    tile(kt, false);
  }
  __syncthreads();
  tile(qt, true);

  l_i += __shfl_xor(l_i, 16);
  l_i += __shfl_xor(l_i, 32);
  float invl = 1.0f / l_i;

#pragma unroll
  for (int r = 0; r < 4; r++) {
    float inv = __shfl(invl, quad * 4 + r);
    size_t row = (size_t)(b * 2048 + qt * 64 + wave * 16 + quad * 4 + r);
#pragma unroll
    for (int nb = 0; nb < 4; nb++)
      ctx[row * 1024 + h * 64 + nb * 16 + col] = f2bf(o_acc[nb][r] * inv);
  }
}

// ---------------------------------------------------------------------------
extern "C" void kernel_launch(void* const* d_in, const int* in_sizes, int n_in,
                              void* d_out, int out_size, void* d_ws, size_t ws_size,
                              hipStream_t stream) {
  const float* X  = (const float*)d_in[0];
  const int* pos  = (const int*)d_in[1];
  const float* wq = (const float*)d_in[2];
  const float* wk = (const float*)d_in[3];
  const float* wv = (const float*)d_in[4];
  const float* wo = (const float*)d_in[5];
  float* out = (float*)d_out;

  short* Xb  = (short*)d_ws;
  short* Wqb = Xb + (1 << 22);
  short* Wkb = Wqb + (1 << 20);
  short* Wvb = Wkb + (1 << 20);
  short* Wob = Wvb + (1 << 20);
  short* Qb  = Wob + (1 << 20);
  short* Kb  = Qb + (1 << 22);
  short* Vtb = Kb + (1 << 22);
  short* Ctx = Vtb + (1 << 22);

  cast_all<<<8192, 256, 0, stream>>>((const float4*)X, (const float4*)wq, (const float4*)wk,
                                     (const float4*)wv, (const float4*)wo, Xb, Wqb);
  qkv_gemm<<<dim3(32, 8, 3), 256, 0, stream>>>(Xb, Wqb, Wkb, Wvb, Qb, Kb, Vtb, pos);
  flash_attn<<<dim3(32, 32), 256, 0, stream>>>(Qb, Kb, Vtb, Ctx);
  out_gemm<<<dim3(32, 16), 256, 0, stream>>>(Ctx, Wob, out);
}